// Round 1
// baseline (164.924 us; speedup 1.0000x reference)
//
#include <hip/hip_runtime.h>
#include <math.h>

// Sobel 3D magnitude, separable form.
// x: (2, 32, 64, 128, 128) fp32 -> out same shape.
// gx = Sz*Sy*Dx, gy = Sz*Dy*Sx, gz = Dz*Sy*Sx with S=[1,2,1], D=[1,0,-1].
// out = sqrt(gx^2+gy^2+gz^2+1e-6).

constexpr int W  = 128;
constexpr int H  = 128;
constexpr int DZ = 64;
constexpr int NC = 2 * 32;      // n*c fused
constexpr int TH = 8;           // rows per block
constexpr int HBLKS = H / TH;   // 16
constexpr int LROWS = TH + 2;   // 10 rows incl. y-halo
constexpr int LSTRIDE = 136;    // padded: [pad pad pad zero | w0..w127 | zero pad pad pad]
constexpr int CBASE = 4;        // interior base column (16B aligned)

__global__ __launch_bounds__(256, 4)
void sobel3d_kernel(const float* __restrict__ xg, float* __restrict__ og) {
    const int tid = threadIdx.x;
    const int tx  = tid & 31;     // w segment: pixels 4*tx .. 4*tx+3
    const int ty  = tid >> 5;     // row within tile (0..7)
    const int hblk = blockIdx.x % HBLKS;
    const int nc   = blockIdx.x / HBLKS;
    const int h0   = hblk * TH;

    const float* __restrict__ xp = xg + (size_t)nc * DZ * H * W;
    float* __restrict__ op       = og + (size_t)nc * DZ * H * W;

    __shared__ float lds[LROWS][LSTRIDE];

    // Zero the constant w-halo columns once (w=-1 and w=128 are zero pad for all z).
    if (tid < LROWS) {
        lds[tid][CBASE - 1] = 0.f;
        lds[tid][CBASE + W] = 0.f;
    }

    // rolling 3-plane state per pixel: slot0 = z-1, slot1 = z, slot2 = z+1
    float c0[4], c1[4], c2[4];   // Sy(Sx)
    float d0[4], d1[4], d2[4];   // Dy(Sx)
    float e0[4], e1[4], e2[4];   // Sy(Dx)
#pragma unroll
    for (int i = 0; i < 4; ++i) {
        c0[i] = c1[i] = 0.f;
        d0[i] = d1[i] = 0.f;
        e0[i] = e1[i] = 0.f;
    }

    // Stage raw plane z into LDS (10 rows x 128 cols, float4 loads; zero-fill halos).
    auto load_plane = [&](int z) {
#pragma unroll
        for (int s0 = 0; s0 < 2; ++s0) {
            int s = tid + s0 * 256;
            if (s < LROWS * 32) {
                int row = s >> 5;
                int seg = s & 31;
                int h = h0 - 1 + row;
                float4 v = make_float4(0.f, 0.f, 0.f, 0.f);
                if (h >= 0 && h < H && z < DZ) {
                    v = *(const float4*)(xp + ((size_t)z * H + h) * W + seg * 4);
                }
                *(float4*)(&lds[row][CBASE + seg * 4]) = v;
            }
        }
    };

    // Per-plane xy-separable intermediates for this thread's 4 pixels.
    auto compute_plane = [&](float* c, float* d, float* e) {
        const int base = CBASE + 4 * tx;
        float sA[4], dA[4], sB[4], dB[4], sC[4], dC[4];
        {
            const float* r = &lds[ty][base - 1];      // h-1
#pragma unroll
            for (int i = 0; i < 4; ++i) { sA[i] = r[i] + 2.f * r[i + 1] + r[i + 2]; dA[i] = r[i] - r[i + 2]; }
        }
        {
            const float* r = &lds[ty + 1][base - 1];  // h
#pragma unroll
            for (int i = 0; i < 4; ++i) { sB[i] = r[i] + 2.f * r[i + 1] + r[i + 2]; dB[i] = r[i] - r[i + 2]; }
        }
        {
            const float* r = &lds[ty + 2][base - 1];  // h+1
#pragma unroll
            for (int i = 0; i < 4; ++i) { sC[i] = r[i] + 2.f * r[i + 1] + r[i + 2]; dC[i] = r[i] - r[i + 2]; }
        }
#pragma unroll
        for (int i = 0; i < 4; ++i) {
            c[i] = sA[i] + 2.f * sB[i] + sC[i];  // Sy(Sx)
            d[i] = sA[i] - sC[i];                // Dy(Sx)
            e[i] = dA[i] + 2.f * dB[i] + dC[i];  // Sy(Dx)
        }
    };

    // Prologue: plane 0 -> slot1 (z=-1 slot0 stays zero).
    load_plane(0);
    __syncthreads();
    compute_plane(c1, d1, e1);

    for (int z = 0; z < DZ; ++z) {
        __syncthreads();            // prior compute done before LDS overwrite
        load_plane(z + 1);          // z+1 == DZ -> zero fill
        __syncthreads();
        compute_plane(c2, d2, e2);

        // emit output for plane z
        float4 o;
        float r[4];
#pragma unroll
        for (int i = 0; i < 4; ++i) {
            float gx = e0[i] + 2.f * e1[i] + e2[i];
            float gy = d0[i] + 2.f * d1[i] + d2[i];
            float gz = c0[i] - c2[i];
            r[i] = sqrtf(gx * gx + gy * gy + gz * gz + 1e-6f);
        }
        o.x = r[0]; o.y = r[1]; o.z = r[2]; o.w = r[3];
        *(float4*)(op + ((size_t)z * H + (h0 + ty)) * W + 4 * tx) = o;

        // shift rolling window
#pragma unroll
        for (int i = 0; i < 4; ++i) {
            c0[i] = c1[i]; c1[i] = c2[i];
            d0[i] = d1[i]; d1[i] = d2[i];
            e0[i] = e1[i]; e1[i] = e2[i];
        }
    }
}

extern "C" void kernel_launch(void* const* d_in, const int* in_sizes, int n_in,
                              void* d_out, int out_size, void* d_ws, size_t ws_size,
                              hipStream_t stream) {
    const float* x = (const float*)d_in[0];
    float* out = (float*)d_out;
    // kernels d_in[1..3] are fixed Sobel constants -> hardcoded in the kernel.
    dim3 grid(NC * HBLKS);   // 2*32*16 = 1024 blocks
    dim3 block(256);
    sobel3d_kernel<<<grid, block, 0, stream>>>(x, out);
}